// Round 1
// baseline (640.948 us; speedup 1.0000x reference)
//
#include <hip/hip_runtime.h>

#define IN_FEATS 256
#define HID 64
#define OUTF 32
#define JK (3*HID)

// ---------------- degree count ----------------
__global__ void deg_kernel(const int* __restrict__ src, const int* __restrict__ dst,
                           int* __restrict__ cnt_out, int* __restrict__ cnt_in, int E) {
    int i = blockIdx.x * blockDim.x + threadIdx.x;
    int stride = gridDim.x * blockDim.x;
    for (int e = i; e < E; e += stride) {
        atomicAdd(&cnt_out[src[e]], 1);
        atomicAdd(&cnt_in[dst[e]], 1);
    }
}

__global__ void scale_kernel(const int* __restrict__ cnt_out, const int* __restrict__ cnt_in,
                             float* __restrict__ do_isqrt, float* __restrict__ di_isqrt, int N) {
    int i = blockIdx.x * blockDim.x + threadIdx.x;
    if (i < N) {
        int co = cnt_out[i]; if (co < 1) co = 1;
        int ci = cnt_in[i];  if (ci < 1) ci = 1;
        do_isqrt[i] = rsqrtf((float)co);
        di_isqrt[i] = rsqrtf((float)ci);
    }
}

// ---------------- exclusive scan (3-kernel) ----------------
__global__ void scan1(const int* __restrict__ cnt, int* __restrict__ indptr,
                      int* __restrict__ bsum, int N) {
    __shared__ int s[256];
    int i = blockIdx.x * 256 + threadIdx.x;
    int v = (i < N) ? cnt[i] : 0;
    s[threadIdx.x] = v;
    __syncthreads();
    for (int off = 1; off < 256; off <<= 1) {
        int t = (threadIdx.x >= off) ? s[threadIdx.x - off] : 0;
        __syncthreads();
        s[threadIdx.x] += t;
        __syncthreads();
    }
    if (i < N) indptr[i] = s[threadIdx.x] - v;   // exclusive
    if (threadIdx.x == 255) bsum[blockIdx.x] = s[255];
}

__global__ void scan2(const int* __restrict__ bsum, int* __restrict__ boff, int nb) {
    __shared__ int s[512];
    int v = ((int)threadIdx.x < nb) ? bsum[threadIdx.x] : 0;
    s[threadIdx.x] = v;
    __syncthreads();
    for (int off = 1; off < 512; off <<= 1) {
        int t = (threadIdx.x >= off) ? s[threadIdx.x - off] : 0;
        __syncthreads();
        s[threadIdx.x] += t;
        __syncthreads();
    }
    boff[threadIdx.x] = s[threadIdx.x] - v;      // exclusive
}

__global__ void scan3(int* __restrict__ indptr, const int* __restrict__ boff, int N, int E) {
    int i = blockIdx.x * 256 + threadIdx.x;
    if (i < N) indptr[i] += boff[blockIdx.x];
    if (i == 0) indptr[N] = E;
}

// ---------------- CSR edge scatter ----------------
__global__ void scatter_kernel(const int* __restrict__ src, const int* __restrict__ dst,
                               const int* __restrict__ indptr, int* __restrict__ cursor,
                               int* __restrict__ colbuf, int E) {
    int i = blockIdx.x * blockDim.x + threadIdx.x;
    int stride = gridDim.x * blockDim.x;
    for (int e = i; e < E; e += stride) {
        int d = dst[e];
        int p = atomicAdd(&cursor[d], 1);
        colbuf[indptr[d] + p] = src[e];
    }
}

// ---------------- GEMM: out[N,COLS] = (X .* rowscale) @ W ----------------
// W is [K][COLS] row-major. KC=64 K-chunks staged in LDS; X staged transposed.
template <int COLS, int K>
__global__ __launch_bounds__(256) void gemm_kernel(
    const float* __restrict__ X, int ldx,
    const float* __restrict__ W,
    const float* __restrict__ rowscale,   // may be null
    float* __restrict__ out, int ldo, int nrows) {
    constexpr int KC = 64;
    constexpr int TX = COLS / 4;       // 16 or 8
    constexpr int TY = 256 / TX;       // 16 or 32
    constexpr int ROWS = TY * 4;       // 64 or 128
    __shared__ float Wl[KC][COLS + 4];
    __shared__ float Xt[KC][ROWS + 4];

    const int tid = threadIdx.x;
    const int tx = tid % TX, ty = tid / TX;
    const int gr0 = blockIdx.x * ROWS;

    float acc[4][4] = {};

    for (int kc = 0; kc < K; kc += KC) {
        // stage W chunk [KC][COLS]
        for (int t = tid; t < KC * COLS / 4; t += 256) {
            int k = t / (COLS / 4), cq = t % (COLS / 4);
            float4 w = *(const float4*)&W[(size_t)(kc + k) * COLS + cq * 4];
            *(float4*)&Wl[k][cq * 4] = w;
        }
        // stage X chunk transposed [KC][ROWS], with row scaling
        for (int t = tid; t < ROWS * (KC / 4); t += 256) {
            int row = t >> 4, kq = t & 15;
            int gr = gr0 + row;
            float4 x = make_float4(0.f, 0.f, 0.f, 0.f);
            float sc = 1.0f;
            if (gr < nrows) {
                x = *(const float4*)&X[(size_t)gr * ldx + kc + kq * 4];
                if (rowscale) sc = rowscale[gr];
            }
            Xt[kq * 4 + 0][row] = x.x * sc;
            Xt[kq * 4 + 1][row] = x.y * sc;
            Xt[kq * 4 + 2][row] = x.z * sc;
            Xt[kq * 4 + 3][row] = x.w * sc;
        }
        __syncthreads();
        #pragma unroll 8
        for (int k = 0; k < KC; ++k) {
            float4 a = *(const float4*)&Xt[k][ty * 4];
            float4 b = *(const float4*)&Wl[k][tx * 4];
            float a4[4] = {a.x, a.y, a.z, a.w};
            float b4[4] = {b.x, b.y, b.z, b.w};
            #pragma unroll
            for (int i = 0; i < 4; ++i)
                #pragma unroll
                for (int j = 0; j < 4; ++j)
                    acc[i][j] = fmaf(a4[i], b4[j], acc[i][j]);
        }
        __syncthreads();
    }

    #pragma unroll
    for (int i = 0; i < 4; ++i) {
        int r = gr0 + ty * 4 + i;
        if (r < nrows) {
            float4 o = make_float4(acc[i][0], acc[i][1], acc[i][2], acc[i][3]);
            *(float4*)&out[(size_t)r * ldo + tx * 4] = o;
        }
    }
}

// ---------------- CSR gather aggregation (fused scale+bias+relu) ----------------
// One F-lane group per node: out[node][col_off + j] = act(scale[node]*sum_e feat[col[e]][j] + bias[j])
template <int F, bool RELU>
__global__ __launch_bounds__(256) void gather_kernel(
    const int* __restrict__ indptr, const int* __restrict__ colbuf,
    const float* __restrict__ feat,      // [*, F] row-major
    const float* __restrict__ scale,     // may be null
    const float* __restrict__ bias,      // [F]
    float* __restrict__ out, int ldo, int col_off, int N) {
    constexpr int NPB = 256 / F;
    int j = threadIdx.x % F;
    int node = blockIdx.x * NPB + threadIdx.x / F;
    if (node >= N) return;
    int beg = indptr[node], end = indptr[node + 1];
    float acc = 0.f;
    int e = beg;
    for (; e + 4 <= end; e += 4) {
        int c0 = colbuf[e], c1 = colbuf[e + 1], c2 = colbuf[e + 2], c3 = colbuf[e + 3];
        float v0 = feat[(size_t)c0 * F + j];
        float v1 = feat[(size_t)c1 * F + j];
        float v2 = feat[(size_t)c2 * F + j];
        float v3 = feat[(size_t)c3 * F + j];
        acc += (v0 + v1) + (v2 + v3);
    }
    for (; e < end; ++e) acc += feat[(size_t)colbuf[e] * F + j];
    float r = acc * (scale ? scale[node] : 1.0f) + bias[j];
    if (RELU) r = fmaxf(r, 0.f);
    out[(size_t)node * ldo + col_off + j] = r;
}

// ---------------- launch ----------------
extern "C" void kernel_launch(void* const* d_in, const int* in_sizes, int n_in,
                              void* d_out, int out_size, void* d_ws, size_t ws_size,
                              hipStream_t stream) {
    const float* feat = (const float*)d_in[0];
    const int*   src  = (const int*)d_in[1];
    const int*   dst  = (const int*)d_in[2];
    const float* W1   = (const float*)d_in[3];
    const float* b1   = (const float*)d_in[4];
    const float* W2   = (const float*)d_in[5];
    const float* b2   = (const float*)d_in[6];
    const float* W3   = (const float*)d_in[7];
    const float* b3   = (const float*)d_in[8];
    const float* Wm   = (const float*)d_in[9];
    const float* bm   = (const float*)d_in[10];
    float* out = (float*)d_out;

    const int N = in_sizes[0] / IN_FEATS;   // 100000
    const int E = in_sizes[1];              // 1600000

    // workspace carve (each region 256B-aligned); total ~124 MB
    char* wsp = (char*)d_ws;
    auto alloc = [&](size_t elems) {
        void* p = (void*)wsp;
        wsp += ((elems * 4 + 255) / 256) * 256;
        return p;
    };
    int*   cnt_out  = (int*)alloc(N);
    int*   cnt_in   = (int*)alloc(N);
    int*   cursor   = (int*)alloc(N);
    int*   bsum     = (int*)alloc(512);
    int*   boff     = (int*)alloc(512);
    int*   indptr   = (int*)alloc(N + 1);
    int*   colbuf   = (int*)alloc(E);
    float* do_isqrt = (float*)alloc(N);
    float* di_isqrt = (float*)alloc(N);
    float* tmp      = (float*)alloc((size_t)N * HID);
    float* H        = (float*)alloc((size_t)N * JK);
    float* P        = (float*)alloc((size_t)N * OUTF);

    hipMemsetAsync(cnt_out, 0, (size_t)N * 4, stream);
    hipMemsetAsync(cnt_in,  0, (size_t)N * 4, stream);
    hipMemsetAsync(cursor,  0, (size_t)N * 4, stream);

    deg_kernel<<<2048, 256, 0, stream>>>(src, dst, cnt_out, cnt_in, E);
    scale_kernel<<<(N + 255) / 256, 256, 0, stream>>>(cnt_out, cnt_in, do_isqrt, di_isqrt, N);

    int nb = (N + 255) / 256;   // 391 (must be <= 512)
    scan1<<<nb, 256, 0, stream>>>(cnt_in, indptr, bsum, N);
    scan2<<<1, 512, 0, stream>>>(bsum, boff, nb);
    scan3<<<nb, 256, 0, stream>>>(indptr, boff, N, E);
    scatter_kernel<<<2048, 256, 0, stream>>>(src, dst, indptr, cursor, colbuf, E);

    // layer 1
    gemm_kernel<HID, IN_FEATS><<<(N + 63) / 64, 256, 0, stream>>>(feat, IN_FEATS, W1, do_isqrt, tmp, HID, N);
    gather_kernel<HID, true><<<(N + 3) / 4, 256, 0, stream>>>(indptr, colbuf, tmp, di_isqrt, b1, H, JK, 0, N);
    // layer 2
    gemm_kernel<HID, HID><<<(N + 63) / 64, 256, 0, stream>>>(H, JK, W2, do_isqrt, tmp, HID, N);
    gather_kernel<HID, true><<<(N + 3) / 4, 256, 0, stream>>>(indptr, colbuf, tmp, di_isqrt, b2, H, JK, HID, N);
    // layer 3
    gemm_kernel<HID, HID><<<(N + 63) / 64, 256, 0, stream>>>(H + HID, JK, W3, do_isqrt, tmp, HID, N);
    gather_kernel<HID, true><<<(N + 3) / 4, 256, 0, stream>>>(indptr, colbuf, tmp, di_isqrt, b3, H, JK, 2 * HID, N);
    // JK projection BEFORE final aggregation (linearity): P = H @ Wm
    gemm_kernel<OUTF, JK><<<(N + 127) / 128, 256, 0, stream>>>(H, JK, Wm, nullptr, P, OUTF, N);
    // final un-normalized aggregation + bias
    gather_kernel<OUTF, false><<<(N + 7) / 8, 256, 0, stream>>>(indptr, colbuf, P, nullptr, bm, out, OUTF, 0, N);
}

// Round 2
// 554.751 us; speedup vs baseline: 1.1554x; 1.1554x over previous
//
#include <hip/hip_runtime.h>

#define IN_FEATS 256
#define HID 64
#define OUTF 32
#define JK (3*HID)

// ---------------- bf16 helpers (RNE) ----------------
__device__ inline unsigned short f2bf(float f) {
    unsigned u = __float_as_uint(f);
    unsigned r = (u + 0x7fffu + ((u >> 16) & 1u)) >> 16;
    return (unsigned short)r;
}
__device__ inline float bf2f(unsigned short u) {
    return __uint_as_float(((unsigned)u) << 16);
}

// ---------------- degree count + ticket ----------------
// cnt_out[src]++ ; ticket[e] = old cnt_in[dst]++  (position within dst bucket)
__global__ void deg_ticket_kernel(const int* __restrict__ src, const int* __restrict__ dst,
                                  int* __restrict__ cnt_out, int* __restrict__ cnt_in,
                                  int* __restrict__ ticket, int E) {
    int i = blockIdx.x * blockDim.x + threadIdx.x;
    int stride = gridDim.x * blockDim.x;
    for (int e = i; e < E; e += stride) {
        atomicAdd(&cnt_out[src[e]], 1);
        ticket[e] = atomicAdd(&cnt_in[dst[e]], 1);
    }
}

__global__ void scale_kernel(const int* __restrict__ cnt_out, const int* __restrict__ cnt_in,
                             float* __restrict__ do_isqrt, float* __restrict__ di_isqrt, int N) {
    int i = blockIdx.x * blockDim.x + threadIdx.x;
    if (i < N) {
        int co = cnt_out[i]; if (co < 1) co = 1;
        int ci = cnt_in[i];  if (ci < 1) ci = 1;
        do_isqrt[i] = rsqrtf((float)co);
        di_isqrt[i] = rsqrtf((float)ci);
    }
}

// ---------------- exclusive scan (3-kernel) ----------------
__global__ void scan1(const int* __restrict__ cnt, int* __restrict__ indptr,
                      int* __restrict__ bsum, int N) {
    __shared__ int s[256];
    int i = blockIdx.x * 256 + threadIdx.x;
    int v = (i < N) ? cnt[i] : 0;
    s[threadIdx.x] = v;
    __syncthreads();
    for (int off = 1; off < 256; off <<= 1) {
        int t = (threadIdx.x >= off) ? s[threadIdx.x - off] : 0;
        __syncthreads();
        s[threadIdx.x] += t;
        __syncthreads();
    }
    if (i < N) indptr[i] = s[threadIdx.x] - v;   // exclusive
    if (threadIdx.x == 255) bsum[blockIdx.x] = s[255];
}

__global__ void scan2(const int* __restrict__ bsum, int* __restrict__ boff, int nb) {
    __shared__ int s[512];
    int v = ((int)threadIdx.x < nb) ? bsum[threadIdx.x] : 0;
    s[threadIdx.x] = v;
    __syncthreads();
    for (int off = 1; off < 512; off <<= 1) {
        int t = (threadIdx.x >= off) ? s[threadIdx.x - off] : 0;
        __syncthreads();
        s[threadIdx.x] += t;
        __syncthreads();
    }
    boff[threadIdx.x] = s[threadIdx.x] - v;      // exclusive
}

__global__ void scan3(int* __restrict__ indptr, const int* __restrict__ boff, int N, int E) {
    int i = blockIdx.x * 256 + threadIdx.x;
    if (i < N) indptr[i] += boff[blockIdx.x];
    if (i == 0) indptr[N] = E;
}

// ---------------- CSR edge scatter (no atomics — uses tickets) ----------------
__global__ void scatter_kernel(const int* __restrict__ src, const int* __restrict__ dst,
                               const int* __restrict__ ticket, const int* __restrict__ indptr,
                               int* __restrict__ colbuf, int E) {
    int i = blockIdx.x * blockDim.x + threadIdx.x;
    int stride = gridDim.x * blockDim.x;
    for (int e = i; e < E; e += stride) {
        colbuf[indptr[dst[e]] + ticket[e]] = src[e];
    }
}

// ---------------- GEMM: out_bf16[N,COLS] = (X .* rowscale) @ W ----------------
// W is [K][COLS] row-major. KC=64 K-chunks staged in LDS; X staged transposed.
template <int COLS, int K>
__global__ __launch_bounds__(256) void gemm_kernel(
    const float* __restrict__ X, int ldx,
    const float* __restrict__ W,
    const float* __restrict__ rowscale,       // may be null
    unsigned short* __restrict__ out,         // bf16 output
    int ldo, int nrows) {
    constexpr int KC = 64;
    constexpr int TX = COLS / 4;       // 16 or 8
    constexpr int TY = 256 / TX;       // 16 or 32
    constexpr int ROWS = TY * 4;       // 64 or 128
    __shared__ float Wl[KC][COLS + 4];
    __shared__ float Xt[KC][ROWS + 4];

    const int tid = threadIdx.x;
    const int tx = tid % TX, ty = tid / TX;
    const int gr0 = blockIdx.x * ROWS;

    float acc[4][4] = {};

    for (int kc = 0; kc < K; kc += KC) {
        for (int t = tid; t < KC * COLS / 4; t += 256) {
            int k = t / (COLS / 4), cq = t % (COLS / 4);
            float4 w = *(const float4*)&W[(size_t)(kc + k) * COLS + cq * 4];
            *(float4*)&Wl[k][cq * 4] = w;
        }
        for (int t = tid; t < ROWS * (KC / 4); t += 256) {
            int row = t >> 4, kq = t & 15;
            int gr = gr0 + row;
            float4 x = make_float4(0.f, 0.f, 0.f, 0.f);
            float sc = 1.0f;
            if (gr < nrows) {
                x = *(const float4*)&X[(size_t)gr * ldx + kc + kq * 4];
                if (rowscale) sc = rowscale[gr];
            }
            Xt[kq * 4 + 0][row] = x.x * sc;
            Xt[kq * 4 + 1][row] = x.y * sc;
            Xt[kq * 4 + 2][row] = x.z * sc;
            Xt[kq * 4 + 3][row] = x.w * sc;
        }
        __syncthreads();
        #pragma unroll 8
        for (int k = 0; k < KC; ++k) {
            float4 a = *(const float4*)&Xt[k][ty * 4];
            float4 b = *(const float4*)&Wl[k][tx * 4];
            float a4[4] = {a.x, a.y, a.z, a.w};
            float b4[4] = {b.x, b.y, b.z, b.w};
            #pragma unroll
            for (int i = 0; i < 4; ++i)
                #pragma unroll
                for (int j = 0; j < 4; ++j)
                    acc[i][j] = fmaf(a4[i], b4[j], acc[i][j]);
        }
        __syncthreads();
    }

    #pragma unroll
    for (int i = 0; i < 4; ++i) {
        int r = gr0 + ty * 4 + i;
        if (r < nrows) {
            ushort4 o;
            o.x = f2bf(acc[i][0]);
            o.y = f2bf(acc[i][1]);
            o.z = f2bf(acc[i][2]);
            o.w = f2bf(acc[i][3]);
            *(ushort4*)&out[(size_t)r * ldo + tx * 4] = o;
        }
    }
}

// ---------------- CSR gather aggregation (bf16 rows, fused scale+bias+relu) ----------------
// One F-lane group per node: out[node][col_off+j] = act(scale[node]*sum_e feat[col[e]][j] + bias[j])
template <int F, bool RELU>
__global__ __launch_bounds__(256) void gather_kernel(
    const int* __restrict__ indptr, const int* __restrict__ colbuf,
    const unsigned short* __restrict__ feat,   // bf16 [*, F] row-major
    const float* __restrict__ scale,           // may be null
    const float* __restrict__ bias,            // [F]
    float* __restrict__ out, int ldo, int col_off, int N) {
    constexpr int NPB = 256 / F;
    int j = threadIdx.x % F;
    int node = blockIdx.x * NPB + threadIdx.x / F;
    if (node >= N) return;
    int beg = indptr[node], end = indptr[node + 1];
    float acc = 0.f;
    int e = beg;
    for (; e + 4 <= end; e += 4) {
        int c0 = colbuf[e], c1 = colbuf[e + 1], c2 = colbuf[e + 2], c3 = colbuf[e + 3];
        float v0 = bf2f(feat[(size_t)c0 * F + j]);
        float v1 = bf2f(feat[(size_t)c1 * F + j]);
        float v2 = bf2f(feat[(size_t)c2 * F + j]);
        float v3 = bf2f(feat[(size_t)c3 * F + j]);
        acc += (v0 + v1) + (v2 + v3);
    }
    for (; e < end; ++e) acc += bf2f(feat[(size_t)colbuf[e] * F + j]);
    float r = acc * (scale ? scale[node] : 1.0f) + bias[j];
    if (RELU) r = fmaxf(r, 0.f);
    out[(size_t)node * ldo + col_off + j] = r;
}

// ---------------- launch ----------------
extern "C" void kernel_launch(void* const* d_in, const int* in_sizes, int n_in,
                              void* d_out, int out_size, void* d_ws, size_t ws_size,
                              hipStream_t stream) {
    const float* feat = (const float*)d_in[0];
    const int*   src  = (const int*)d_in[1];
    const int*   dst  = (const int*)d_in[2];
    const float* W1   = (const float*)d_in[3];
    const float* b1   = (const float*)d_in[4];
    const float* W2   = (const float*)d_in[5];
    const float* b2   = (const float*)d_in[6];
    const float* W3   = (const float*)d_in[7];
    const float* b3   = (const float*)d_in[8];
    const float* Wm   = (const float*)d_in[9];
    const float* bm   = (const float*)d_in[10];
    float* out = (float*)d_out;

    const int N = in_sizes[0] / IN_FEATS;   // 100000
    const int E = in_sizes[1];              // 1600000

    // workspace carve (each region 256B-aligned)
    char* wsp = (char*)d_ws;
    auto alloc = [&](size_t bytes) {
        void* p = (void*)wsp;
        wsp += ((bytes + 255) / 256) * 256;
        return p;
    };
    int*   cnt_out  = (int*)alloc((size_t)N * 4);
    int*   cnt_in   = (int*)alloc((size_t)N * 4);
    int*   bsum     = (int*)alloc(512 * 4);
    int*   boff     = (int*)alloc(512 * 4);
    int*   indptr   = (int*)alloc((size_t)(N + 1) * 4);
    int*   ticket   = (int*)alloc((size_t)E * 4);
    int*   colbuf   = (int*)alloc((size_t)E * 4);
    float* do_isqrt = (float*)alloc((size_t)N * 4);
    float* di_isqrt = (float*)alloc((size_t)N * 4);
    unsigned short* tmp = (unsigned short*)alloc((size_t)N * HID * 2);   // bf16
    float* H        = (float*)alloc((size_t)N * JK * 4);
    unsigned short* P = (unsigned short*)alloc((size_t)N * OUTF * 2);    // bf16

    hipMemsetAsync(cnt_out, 0, (size_t)N * 4, stream);
    hipMemsetAsync(cnt_in,  0, (size_t)N * 4, stream);

    deg_ticket_kernel<<<2048, 256, 0, stream>>>(src, dst, cnt_out, cnt_in, ticket, E);
    scale_kernel<<<(N + 255) / 256, 256, 0, stream>>>(cnt_out, cnt_in, do_isqrt, di_isqrt, N);

    int nb = (N + 255) / 256;   // 391 (must be <= 512)
    scan1<<<nb, 256, 0, stream>>>(cnt_in, indptr, bsum, N);
    scan2<<<1, 512, 0, stream>>>(bsum, boff, nb);
    scan3<<<nb, 256, 0, stream>>>(indptr, boff, N, E);
    scatter_kernel<<<2048, 256, 0, stream>>>(src, dst, ticket, indptr, colbuf, E);

    // layer 1
    gemm_kernel<HID, IN_FEATS><<<(N + 63) / 64, 256, 0, stream>>>(feat, IN_FEATS, W1, do_isqrt, tmp, HID, N);
    gather_kernel<HID, true><<<(N + 3) / 4, 256, 0, stream>>>(indptr, colbuf, tmp, di_isqrt, b1, H, JK, 0, N);
    // layer 2
    gemm_kernel<HID, HID><<<(N + 63) / 64, 256, 0, stream>>>(H, JK, W2, do_isqrt, tmp, HID, N);
    gather_kernel<HID, true><<<(N + 3) / 4, 256, 0, stream>>>(indptr, colbuf, tmp, di_isqrt, b2, H, JK, HID, N);
    // layer 3
    gemm_kernel<HID, HID><<<(N + 63) / 64, 256, 0, stream>>>(H + HID, JK, W3, do_isqrt, tmp, HID, N);
    gather_kernel<HID, true><<<(N + 3) / 4, 256, 0, stream>>>(indptr, colbuf, tmp, di_isqrt, b3, H, JK, 2 * HID, N);
    // JK projection BEFORE final aggregation (linearity): P = H @ Wm
    gemm_kernel<OUTF, JK><<<(N + 127) / 128, 256, 0, stream>>>(H, JK, Wm, nullptr, P, OUTF, N);
    // final un-normalized aggregation + bias
    gather_kernel<OUTF, false><<<(N + 7) / 8, 256, 0, stream>>>(indptr, colbuf, P, nullptr, bm, out, OUTF, 0, N);
}

// Round 3
// 483.429 us; speedup vs baseline: 1.3258x; 1.1475x over previous
//
#include <hip/hip_runtime.h>

#define IN_FEATS 256
#define HID 64
#define OUTF 32
#define JK (3*HID)

#define NB   256   // buckets (allocated); actual used = (N+511)>>9
#define BSH  9     // bucket covers 512 nodes
#define NBLK 512   // edge-chunk blocks for hist/scatter

// ---------------- bf16 helpers (RNE) ----------------
__device__ inline unsigned short f2bf(float f) {
    unsigned u = __float_as_uint(f);
    unsigned r = (u + 0x7fffu + ((u >> 16) & 1u)) >> 16;
    return (unsigned short)r;
}
__device__ inline float bf2f(unsigned short u) {
    return __uint_as_float(((unsigned)u) << 16);
}

// ---------------- P1: per-block LDS histograms over dst-buckets and src-buckets ----
__global__ __launch_bounds__(256) void p1_hist(const int* __restrict__ src,
                                               const int* __restrict__ dst, int E,
                                               int* __restrict__ bhd, int* __restrict__ bhs) {
    __shared__ int hd[NB], hs[NB];
    int b = blockIdx.x;
    for (int t = threadIdx.x; t < NB; t += 256) { hd[t] = 0; hs[t] = 0; }
    __syncthreads();
    int cb = (E + NBLK - 1) / NBLK;
    int beg = b * cb, end = min(beg + cb, E);
    for (int e = beg + threadIdx.x; e < end; e += 256) {
        atomicAdd(&hd[dst[e] >> BSH], 1);
        atomicAdd(&hs[src[e] >> BSH], 1);
    }
    __syncthreads();
    for (int t = threadIdx.x; t < NB; t += 256) {
        bhd[b * NB + t] = hd[t];
        bhs[b * NB + t] = hs[t];
    }
}

// ---------------- P2: convert block-histograms to global scatter offsets (in place) ----
// grid = 2 blocks: block 0 handles dst-side, block 1 handles src-side.
__global__ __launch_bounds__(256) void p2_offsets(int* __restrict__ bhd, int* __restrict__ bhs,
                                                  int* __restrict__ based, int* __restrict__ bases,
                                                  int nblk) {
    __shared__ int s[256];
    int* bh = blockIdx.x ? bhs : bhd;
    int* bb = blockIdx.x ? bases : based;
    int t = threadIdx.x;
    int tot = 0;
    for (int k = 0; k < nblk; ++k) tot += bh[k * NB + t];
    s[t] = tot;
    __syncthreads();
    for (int off = 1; off < 256; off <<= 1) {
        int v = (t >= off) ? s[t - off] : 0;
        __syncthreads();
        s[t] += v;
        __syncthreads();
    }
    int base = s[t] - tot;      // exclusive prefix over buckets
    bb[t] = base;
    if (t == 255) bb[256] = s[255];
    int run = base;
    for (int k = 0; k < nblk; ++k) {
        int v = bh[k * NB + t];
        bh[k * NB + t] = run;   // global offset for (block k, bucket t)
        run += v;
    }
}

// ---------------- P3: partition edges by bucket (LDS cursors, no global atomics) ----
__global__ __launch_bounds__(256) void p3_scatter(const int* __restrict__ src,
                                                  const int* __restrict__ dst, int E,
                                                  const int* __restrict__ bhd,
                                                  const int* __restrict__ bhs,
                                                  int2* __restrict__ pairbuf,
                                                  int* __restrict__ srctmp) {
    __shared__ int curd[NB], curs[NB];
    int b = blockIdx.x;
    for (int t = threadIdx.x; t < NB; t += 256) {
        curd[t] = bhd[b * NB + t];
        curs[t] = bhs[b * NB + t];
    }
    __syncthreads();
    int cb = (E + NBLK - 1) / NBLK;
    int beg = b * cb, end = min(beg + cb, E);
    for (int e = beg + threadIdx.x; e < end; e += 256) {
        int d = dst[e], sv = src[e];
        int pd = atomicAdd(&curd[d >> BSH], 1);
        pairbuf[pd] = make_int2(d, sv);
        int ps = atomicAdd(&curs[sv >> BSH], 1);
        srctmp[ps] = sv;
    }
}

// ---------------- P4: per-bucket CSR build (count -> scan -> place) ----------------
__global__ __launch_bounds__(256) void p4_csr(const int2* __restrict__ pairbuf,
                                              const int* __restrict__ based,
                                              int* __restrict__ indptr, int* __restrict__ cnt_in,
                                              int* __restrict__ colbuf, int N, int E) {
    __shared__ int cnt[512], lp[512], s[256];
    int b = blockIdx.x;
    int nbase = b << BSH;
    int nn = min(512, N - nbase);
    int t = threadIdx.x;
    cnt[t] = 0; cnt[t + 256] = 0;
    __syncthreads();
    int eb = based[b], ee = based[b + 1];
    for (int e = eb + t; e < ee; e += 256)
        atomicAdd(&cnt[pairbuf[e].x - nbase], 1);
    __syncthreads();
    // exclusive scan over 512 counts (thread t owns 2t, 2t+1)
    int a0 = cnt[2 * t], a1 = cnt[2 * t + 1];
    int psum = a0 + a1;
    s[t] = psum;
    __syncthreads();
    for (int off = 1; off < 256; off <<= 1) {
        int v = (t >= off) ? s[t - off] : 0;
        __syncthreads();
        s[t] += v;
        __syncthreads();
    }
    int ebase = s[t] - psum;
    lp[2 * t] = ebase;
    lp[2 * t + 1] = ebase + a0;
    __syncthreads();
    for (int i = t; i < nn; i += 256) {
        indptr[nbase + i] = eb + lp[i];
        cnt_in[nbase + i] = cnt[i];
    }
    if (b == 0 && t == 0) indptr[N] = E;
    __syncthreads();
    // place edges using lp as cursors
    for (int e = eb + t; e < ee; e += 256) {
        int2 p = pairbuf[e];
        int pos = atomicAdd(&lp[p.x - nbase], 1);
        colbuf[eb + pos] = p.y;
    }
}

// ---------------- P4s: per-bucket out-degree counts ----------------
__global__ __launch_bounds__(256) void p4s_cnt(const int* __restrict__ srctmp,
                                               const int* __restrict__ bases,
                                               int* __restrict__ cnt_out, int N) {
    __shared__ int cnt[512];
    int b = blockIdx.x;
    int nbase = b << BSH;
    int nn = min(512, N - nbase);
    int t = threadIdx.x;
    cnt[t] = 0; cnt[t + 256] = 0;
    __syncthreads();
    int eb = bases[b], ee = bases[b + 1];
    for (int e = eb + t; e < ee; e += 256)
        atomicAdd(&cnt[srctmp[e] - nbase], 1);
    __syncthreads();
    for (int i = t; i < nn; i += 256) cnt_out[nbase + i] = cnt[i];
}

__global__ void scale_kernel(const int* __restrict__ cnt_out, const int* __restrict__ cnt_in,
                             float* __restrict__ do_isqrt, float* __restrict__ di_isqrt, int N) {
    int i = blockIdx.x * blockDim.x + threadIdx.x;
    if (i < N) {
        int co = cnt_out[i]; if (co < 1) co = 1;
        int ci = cnt_in[i];  if (ci < 1) ci = 1;
        do_isqrt[i] = rsqrtf((float)co);
        di_isqrt[i] = rsqrtf((float)ci);
    }
}

// ---------------- GEMM: out_bf16[N,COLS] = (X .* rowscale) @ W ----------------
template <int COLS, int K>
__global__ __launch_bounds__(256) void gemm_kernel(
    const float* __restrict__ X, int ldx,
    const float* __restrict__ W,
    const float* __restrict__ rowscale,       // may be null
    unsigned short* __restrict__ out,         // bf16 output
    int ldo, int nrows) {
    constexpr int KC = 64;
    constexpr int TX = COLS / 4;       // 16 or 8
    constexpr int TY = 256 / TX;       // 16 or 32
    constexpr int ROWS = TY * 4;       // 64 or 128
    __shared__ float Wl[KC][COLS + 4];
    __shared__ float Xt[KC][ROWS + 4];

    const int tid = threadIdx.x;
    const int tx = tid % TX, ty = tid / TX;
    const int gr0 = blockIdx.x * ROWS;

    float acc[4][4] = {};

    for (int kc = 0; kc < K; kc += KC) {
        for (int t = tid; t < KC * COLS / 4; t += 256) {
            int k = t / (COLS / 4), cq = t % (COLS / 4);
            float4 w = *(const float4*)&W[(size_t)(kc + k) * COLS + cq * 4];
            *(float4*)&Wl[k][cq * 4] = w;
        }
        for (int t = tid; t < ROWS * (KC / 4); t += 256) {
            int row = t >> 4, kq = t & 15;
            int gr = gr0 + row;
            float4 x = make_float4(0.f, 0.f, 0.f, 0.f);
            float sc = 1.0f;
            if (gr < nrows) {
                x = *(const float4*)&X[(size_t)gr * ldx + kc + kq * 4];
                if (rowscale) sc = rowscale[gr];
            }
            Xt[kq * 4 + 0][row] = x.x * sc;
            Xt[kq * 4 + 1][row] = x.y * sc;
            Xt[kq * 4 + 2][row] = x.z * sc;
            Xt[kq * 4 + 3][row] = x.w * sc;
        }
        __syncthreads();
        #pragma unroll 8
        for (int k = 0; k < KC; ++k) {
            float4 a = *(const float4*)&Xt[k][ty * 4];
            float4 b = *(const float4*)&Wl[k][tx * 4];
            float a4[4] = {a.x, a.y, a.z, a.w};
            float b4[4] = {b.x, b.y, b.z, b.w};
            #pragma unroll
            for (int i = 0; i < 4; ++i)
                #pragma unroll
                for (int j = 0; j < 4; ++j)
                    acc[i][j] = fmaf(a4[i], b4[j], acc[i][j]);
        }
        __syncthreads();
    }

    #pragma unroll
    for (int i = 0; i < 4; ++i) {
        int r = gr0 + ty * 4 + i;
        if (r < nrows) {
            ushort4 o;
            o.x = f2bf(acc[i][0]);
            o.y = f2bf(acc[i][1]);
            o.z = f2bf(acc[i][2]);
            o.w = f2bf(acc[i][3]);
            *(ushort4*)&out[(size_t)r * ldo + tx * 4] = o;
        }
    }
}

// ---------------- CSR gather aggregation (bf16x2 rows, fused scale+bias+relu) -------
// F/2 lanes per node; lane j handles columns 2j, 2j+1.
template <int F, bool RELU>
__global__ __launch_bounds__(256) void gather_kernel(
    const int* __restrict__ indptr, const int* __restrict__ colbuf,
    const unsigned int* __restrict__ feat,     // bf16x2 [*, F/2]
    const float* __restrict__ scale,           // may be null
    const float* __restrict__ bias,            // [F]
    float* __restrict__ out, int ldo, int col_off, int N) {
    constexpr int L = F / 2;
    constexpr int NPB = 256 / L;
    int j = threadIdx.x % L;
    int node = blockIdx.x * NPB + threadIdx.x / L;
    if (node >= N) return;
    int beg = indptr[node], end = indptr[node + 1];
    float a0 = 0.f, a1 = 0.f;
    int e = beg;
    for (; e + 4 <= end; e += 4) {
        int c0 = colbuf[e], c1 = colbuf[e + 1], c2 = colbuf[e + 2], c3 = colbuf[e + 3];
        unsigned u0 = feat[(size_t)c0 * L + j];
        unsigned u1 = feat[(size_t)c1 * L + j];
        unsigned u2 = feat[(size_t)c2 * L + j];
        unsigned u3 = feat[(size_t)c3 * L + j];
        a0 += (bf2f(u0 & 0xffff) + bf2f(u1 & 0xffff)) + (bf2f(u2 & 0xffff) + bf2f(u3 & 0xffff));
        a1 += (bf2f((unsigned short)(u0 >> 16)) + bf2f((unsigned short)(u1 >> 16)))
            + (bf2f((unsigned short)(u2 >> 16)) + bf2f((unsigned short)(u3 >> 16)));
    }
    for (; e < end; ++e) {
        unsigned u = feat[(size_t)colbuf[e] * L + j];
        a0 += bf2f(u & 0xffff);
        a1 += bf2f((unsigned short)(u >> 16));
    }
    float sc = scale ? scale[node] : 1.0f;
    float r0 = a0 * sc + bias[2 * j];
    float r1 = a1 * sc + bias[2 * j + 1];
    if (RELU) { r0 = fmaxf(r0, 0.f); r1 = fmaxf(r1, 0.f); }
    *(float2*)&out[(size_t)node * ldo + col_off + 2 * j] = make_float2(r0, r1);
}

// ---------------- launch ----------------
extern "C" void kernel_launch(void* const* d_in, const int* in_sizes, int n_in,
                              void* d_out, int out_size, void* d_ws, size_t ws_size,
                              hipStream_t stream) {
    const float* feat = (const float*)d_in[0];
    const int*   src  = (const int*)d_in[1];
    const int*   dst  = (const int*)d_in[2];
    const float* W1   = (const float*)d_in[3];
    const float* b1   = (const float*)d_in[4];
    const float* W2   = (const float*)d_in[5];
    const float* b2   = (const float*)d_in[6];
    const float* W3   = (const float*)d_in[7];
    const float* b3   = (const float*)d_in[8];
    const float* Wm   = (const float*)d_in[9];
    const float* bm   = (const float*)d_in[10];
    float* out = (float*)d_out;

    const int N = in_sizes[0] / IN_FEATS;   // 100000
    const int E = in_sizes[1];              // 1600000
    const int NBUCK = (N + 511) >> BSH;     // 196

    // workspace carve (256B-aligned regions)
    char* wsp = (char*)d_ws;
    auto alloc = [&](size_t bytes) {
        void* p = (void*)wsp;
        wsp += ((bytes + 255) / 256) * 256;
        return p;
    };
    int*   cnt_out  = (int*)alloc((size_t)N * 4);
    int*   cnt_in   = (int*)alloc((size_t)N * 4);
    int*   indptr   = (int*)alloc((size_t)(N + 1) * 4);
    int*   colbuf   = (int*)alloc((size_t)E * 4);
    int*   bhd      = (int*)alloc((size_t)NBLK * NB * 4);
    int*   bhs      = (int*)alloc((size_t)NBLK * NB * 4);
    int*   based    = (int*)alloc(257 * 4);
    int*   bases    = (int*)alloc(257 * 4);
    float* do_isqrt = (float*)alloc((size_t)N * 4);
    float* di_isqrt = (float*)alloc((size_t)N * 4);
    float* H        = (float*)alloc((size_t)N * JK * 4);
    int2*  pairbuf  = (int2*)alloc((size_t)E * 8);    // aliased by tmp after CSR build
    int*   srctmp   = (int*)alloc((size_t)E * 4);     // aliased by P after cnt build
    unsigned short* tmp = (unsigned short*)pairbuf;   // N*HID bf16 = 12.8MB <= E*8
    unsigned short* P   = (unsigned short*)srctmp;    // N*OUTF bf16 = 6.4MB <= E*4

    // ---- CSR + degree build (no global atomics) ----
    p1_hist<<<NBLK, 256, 0, stream>>>(src, dst, E, bhd, bhs);
    p2_offsets<<<2, 256, 0, stream>>>(bhd, bhs, based, bases, NBLK);
    p3_scatter<<<NBLK, 256, 0, stream>>>(src, dst, E, bhd, bhs, pairbuf, srctmp);
    p4_csr<<<NBUCK, 256, 0, stream>>>(pairbuf, based, indptr, cnt_in, colbuf, N, E);
    p4s_cnt<<<NBUCK, 256, 0, stream>>>(srctmp, bases, cnt_out, N);
    scale_kernel<<<(N + 255) / 256, 256, 0, stream>>>(cnt_out, cnt_in, do_isqrt, di_isqrt, N);

    // ---- layers ----
    gemm_kernel<HID, IN_FEATS><<<(N + 63) / 64, 256, 0, stream>>>(feat, IN_FEATS, W1, do_isqrt, tmp, HID, N);
    gather_kernel<HID, true><<<(N + 7) / 8, 256, 0, stream>>>(indptr, colbuf, (const unsigned int*)tmp, di_isqrt, b1, H, JK, 0, N);
    gemm_kernel<HID, HID><<<(N + 63) / 64, 256, 0, stream>>>(H, JK, W2, do_isqrt, tmp, HID, N);
    gather_kernel<HID, true><<<(N + 7) / 8, 256, 0, stream>>>(indptr, colbuf, (const unsigned int*)tmp, di_isqrt, b2, H, JK, HID, N);
    gemm_kernel<HID, HID><<<(N + 63) / 64, 256, 0, stream>>>(H + HID, JK, W3, do_isqrt, tmp, HID, N);
    gather_kernel<HID, true><<<(N + 7) / 8, 256, 0, stream>>>(indptr, colbuf, (const unsigned int*)tmp, di_isqrt, b3, H, JK, 2 * HID, N);
    // JK projection BEFORE final aggregation (linearity): P = H @ Wm
    gemm_kernel<OUTF, JK><<<(N + 127) / 128, 256, 0, stream>>>(H, JK, Wm, nullptr, P, OUTF, N);
    // final un-normalized aggregation + bias
    gather_kernel<OUTF, false><<<(N + 15) / 16, 256, 0, stream>>>(indptr, colbuf, (const unsigned int*)P, nullptr, bm, out, OUTF, 0, N);
}

// Round 4
// 377.243 us; speedup vs baseline: 1.6990x; 1.2815x over previous
//
#include <hip/hip_runtime.h>

#define IN_FEATS 256
#define HID 64
#define OUTF 32
#define JK (3*HID)

#define NB   256   // buckets (allocated); actual used = (N+511)>>9
#define BSH  9     // bucket covers 512 nodes
#define NBLK 512   // edge-chunk blocks for hist/scatter

// ---------------- bf16 helpers (RNE) ----------------
__device__ inline unsigned short f2bf(float f) {
    unsigned u = __float_as_uint(f);
    unsigned r = (u + 0x7fffu + ((u >> 16) & 1u)) >> 16;
    return (unsigned short)r;
}
__device__ inline float bf2f(unsigned short u) {
    return __uint_as_float(((unsigned)u) << 16);
}

// ---------------- P1: per-block LDS histograms over dst-buckets and src-buckets ----
__global__ __launch_bounds__(256) void p1_hist(const int* __restrict__ src,
                                               const int* __restrict__ dst, int E,
                                               int* __restrict__ bhd, int* __restrict__ bhs) {
    __shared__ int hd[NB], hs[NB];
    int b = blockIdx.x;
    for (int t = threadIdx.x; t < NB; t += 256) { hd[t] = 0; hs[t] = 0; }
    __syncthreads();
    int cb = (E + NBLK - 1) / NBLK;
    int beg = b * cb, end = min(beg + cb, E);
    for (int e = beg + threadIdx.x; e < end; e += 256) {
        atomicAdd(&hd[dst[e] >> BSH], 1);
        atomicAdd(&hs[src[e] >> BSH], 1);
    }
    __syncthreads();
    for (int t = threadIdx.x; t < NB; t += 256) {
        bhd[b * NB + t] = hd[t];
        bhs[b * NB + t] = hs[t];
    }
}

// ---------------- P2a: per-(side,bucket) totals over block-histograms ----------------
__global__ __launch_bounds__(256) void p2a_tot(const int* __restrict__ bhd,
                                               const int* __restrict__ bhs,
                                               int* __restrict__ totd, int* __restrict__ tots,
                                               int nblk) {
    __shared__ int s[256];
    int side = blockIdx.x >> 8;     // grid = 512
    int t = blockIdx.x & 255;
    const int* bh = side ? bhs : bhd;
    int acc = 0;
    for (int k = threadIdx.x; k < nblk; k += 256) acc += bh[k * NB + t];
    s[threadIdx.x] = acc;
    __syncthreads();
    for (int off = 128; off > 0; off >>= 1) {
        if (threadIdx.x < off) s[threadIdx.x] += s[threadIdx.x + off];
        __syncthreads();
    }
    if (threadIdx.x == 0) (side ? tots : totd)[t] = s[0];
}

// ---------------- P2b: exclusive scan over bucket totals -> based/bases ----------------
__global__ __launch_bounds__(256) void p2b_scan(const int* __restrict__ totd,
                                                const int* __restrict__ tots,
                                                int* __restrict__ based, int* __restrict__ bases) {
    __shared__ int s[256];
    const int* tot = blockIdx.x ? tots : totd;
    int* bb = blockIdx.x ? bases : based;
    int t = threadIdx.x;
    int v = tot[t];
    s[t] = v;
    __syncthreads();
    for (int off = 1; off < 256; off <<= 1) {
        int u = (t >= off) ? s[t - off] : 0;
        __syncthreads();
        s[t] += u;
        __syncthreads();
    }
    bb[t] = s[t] - v;
    if (t == 255) bb[256] = s[255];
}

// ---------------- P2c: per-bucket prefix over blocks (in place) ----------------
__global__ __launch_bounds__(256) void p2c_off(int* __restrict__ bhd, int* __restrict__ bhs,
                                               const int* __restrict__ based,
                                               const int* __restrict__ bases, int nblk) {
    __shared__ int s[256];
    int side = blockIdx.x >> 8;     // grid = 512
    int t = blockIdx.x & 255;
    int* bh = side ? bhs : bhd;
    int carry = (side ? bases : based)[t];
    for (int k0 = 0; k0 < nblk; k0 += 256) {
        int k = k0 + threadIdx.x;
        int v = (k < nblk) ? bh[k * NB + t] : 0;
        s[threadIdx.x] = v;
        __syncthreads();
        for (int off = 1; off < 256; off <<= 1) {
            int u = (threadIdx.x >= off) ? s[threadIdx.x - off] : 0;
            __syncthreads();
            s[threadIdx.x] += u;
            __syncthreads();
        }
        if (k < nblk) bh[k * NB + t] = carry + s[threadIdx.x] - v;
        int tot = s[255];
        __syncthreads();
        carry += tot;
    }
}

// ---------------- P3: partition edges by bucket (LDS cursors, no global atomics) ----
__global__ __launch_bounds__(256) void p3_scatter(const int* __restrict__ src,
                                                  const int* __restrict__ dst, int E,
                                                  const int* __restrict__ bhd,
                                                  const int* __restrict__ bhs,
                                                  int2* __restrict__ pairbuf,
                                                  int* __restrict__ srctmp) {
    __shared__ int curd[NB], curs[NB];
    int b = blockIdx.x;
    for (int t = threadIdx.x; t < NB; t += 256) {
        curd[t] = bhd[b * NB + t];
        curs[t] = bhs[b * NB + t];
    }
    __syncthreads();
    int cb = (E + NBLK - 1) / NBLK;
    int beg = b * cb, end = min(beg + cb, E);
    for (int e = beg + threadIdx.x; e < end; e += 256) {
        int d = dst[e], sv = src[e];
        int pd = atomicAdd(&curd[d >> BSH], 1);
        pairbuf[pd] = make_int2(d, sv);
        int ps = atomicAdd(&curs[sv >> BSH], 1);
        srctmp[ps] = sv;
    }
}

// ---------------- P4: per-bucket CSR build (count -> scan -> place) ----------------
__global__ __launch_bounds__(256) void p4_csr(const int2* __restrict__ pairbuf,
                                              const int* __restrict__ based,
                                              int* __restrict__ indptr, int* __restrict__ cnt_in,
                                              int* __restrict__ colbuf, int N, int E) {
    __shared__ int cnt[512], lp[512], s[256];
    int b = blockIdx.x;
    int nbase = b << BSH;
    int nn = min(512, N - nbase);
    int t = threadIdx.x;
    cnt[t] = 0; cnt[t + 256] = 0;
    __syncthreads();
    int eb = based[b], ee = based[b + 1];
    for (int e = eb + t; e < ee; e += 256)
        atomicAdd(&cnt[pairbuf[e].x - nbase], 1);
    __syncthreads();
    // exclusive scan over 512 counts (thread t owns 2t, 2t+1)
    int a0 = cnt[2 * t], a1 = cnt[2 * t + 1];
    int psum = a0 + a1;
    s[t] = psum;
    __syncthreads();
    for (int off = 1; off < 256; off <<= 1) {
        int v = (t >= off) ? s[t - off] : 0;
        __syncthreads();
        s[t] += v;
        __syncthreads();
    }
    int ebase = s[t] - psum;
    lp[2 * t] = ebase;
    lp[2 * t + 1] = ebase + a0;
    __syncthreads();
    for (int i = t; i < nn; i += 256) {
        indptr[nbase + i] = eb + lp[i];
        cnt_in[nbase + i] = cnt[i];
    }
    if (b == 0 && t == 0) indptr[N] = E;
    __syncthreads();
    // place edges using lp as cursors
    for (int e = eb + t; e < ee; e += 256) {
        int2 p = pairbuf[e];
        int pos = atomicAdd(&lp[p.x - nbase], 1);
        colbuf[eb + pos] = p.y;
    }
}

// ---------------- P4s: per-bucket out-degree counts ----------------
__global__ __launch_bounds__(256) void p4s_cnt(const int* __restrict__ srctmp,
                                               const int* __restrict__ bases,
                                               int* __restrict__ cnt_out, int N) {
    __shared__ int cnt[512];
    int b = blockIdx.x;
    int nbase = b << BSH;
    int nn = min(512, N - nbase);
    int t = threadIdx.x;
    cnt[t] = 0; cnt[t + 256] = 0;
    __syncthreads();
    int eb = bases[b], ee = bases[b + 1];
    for (int e = eb + t; e < ee; e += 256)
        atomicAdd(&cnt[srctmp[e] - nbase], 1);
    __syncthreads();
    for (int i = t; i < nn; i += 256) cnt_out[nbase + i] = cnt[i];
}

__global__ void scale_kernel(const int* __restrict__ cnt_out, const int* __restrict__ cnt_in,
                             float* __restrict__ do_isqrt, float* __restrict__ di_isqrt, int N) {
    int i = blockIdx.x * blockDim.x + threadIdx.x;
    if (i < N) {
        int co = cnt_out[i]; if (co < 1) co = 1;
        int ci = cnt_in[i];  if (ci < 1) ci = 1;
        do_isqrt[i] = rsqrtf((float)co);
        di_isqrt[i] = rsqrtf((float)ci);
    }
}

// ---------------- GEMM: out_bf16[N,COLS] = (X .* rowscale) @ W ----------------
template <int COLS, int K>
__global__ __launch_bounds__(256) void gemm_kernel(
    const float* __restrict__ X, int ldx,
    const float* __restrict__ W,
    const float* __restrict__ rowscale,       // may be null
    unsigned short* __restrict__ out,         // bf16 output
    int ldo, int nrows) {
    constexpr int KC = 64;
    constexpr int TX = COLS / 4;       // 16 or 8
    constexpr int TY = 256 / TX;       // 16 or 32
    constexpr int ROWS = TY * 4;       // 64 or 128
    __shared__ float Wl[KC][COLS + 4];
    __shared__ float Xt[KC][ROWS + 4];

    const int tid = threadIdx.x;
    const int tx = tid % TX, ty = tid / TX;
    const int gr0 = blockIdx.x * ROWS;

    float acc[4][4] = {};

    for (int kc = 0; kc < K; kc += KC) {
        for (int t = tid; t < KC * COLS / 4; t += 256) {
            int k = t / (COLS / 4), cq = t % (COLS / 4);
            float4 w = *(const float4*)&W[(size_t)(kc + k) * COLS + cq * 4];
            *(float4*)&Wl[k][cq * 4] = w;
        }
        for (int t = tid; t < ROWS * (KC / 4); t += 256) {
            int row = t >> 4, kq = t & 15;
            int gr = gr0 + row;
            float4 x = make_float4(0.f, 0.f, 0.f, 0.f);
            float sc = 1.0f;
            if (gr < nrows) {
                x = *(const float4*)&X[(size_t)gr * ldx + kc + kq * 4];
                if (rowscale) sc = rowscale[gr];
            }
            Xt[kq * 4 + 0][row] = x.x * sc;
            Xt[kq * 4 + 1][row] = x.y * sc;
            Xt[kq * 4 + 2][row] = x.z * sc;
            Xt[kq * 4 + 3][row] = x.w * sc;
        }
        __syncthreads();
        #pragma unroll 8
        for (int k = 0; k < KC; ++k) {
            float4 a = *(const float4*)&Xt[k][ty * 4];
            float4 b = *(const float4*)&Wl[k][tx * 4];
            float a4[4] = {a.x, a.y, a.z, a.w};
            float b4[4] = {b.x, b.y, b.z, b.w};
            #pragma unroll
            for (int i = 0; i < 4; ++i)
                #pragma unroll
                for (int j = 0; j < 4; ++j)
                    acc[i][j] = fmaf(a4[i], b4[j], acc[i][j]);
        }
        __syncthreads();
    }

    #pragma unroll
    for (int i = 0; i < 4; ++i) {
        int r = gr0 + ty * 4 + i;
        if (r < nrows) {
            ushort4 o;
            o.x = f2bf(acc[i][0]);
            o.y = f2bf(acc[i][1]);
            o.z = f2bf(acc[i][2]);
            o.w = f2bf(acc[i][3]);
            *(ushort4*)&out[(size_t)r * ldo + tx * 4] = o;
        }
    }
}

// ---------------- CSR gather aggregation (bf16x2 rows, fused scale+bias+relu) -------
// F/2 lanes per node; lane j handles columns 2j, 2j+1.
template <int F, bool RELU>
__global__ __launch_bounds__(256) void gather_kernel(
    const int* __restrict__ indptr, const int* __restrict__ colbuf,
    const unsigned int* __restrict__ feat,     // bf16x2 [*, F/2]
    const float* __restrict__ scale,           // may be null
    const float* __restrict__ bias,            // [F]
    float* __restrict__ out, int ldo, int col_off, int N) {
    constexpr int L = F / 2;
    constexpr int NPB = 256 / L;
    int j = threadIdx.x % L;
    int node = blockIdx.x * NPB + threadIdx.x / L;
    if (node >= N) return;
    int beg = indptr[node], end = indptr[node + 1];
    float a0 = 0.f, a1 = 0.f;
    int e = beg;
    for (; e + 4 <= end; e += 4) {
        int c0 = colbuf[e], c1 = colbuf[e + 1], c2 = colbuf[e + 2], c3 = colbuf[e + 3];
        unsigned u0 = feat[(size_t)c0 * L + j];
        unsigned u1 = feat[(size_t)c1 * L + j];
        unsigned u2 = feat[(size_t)c2 * L + j];
        unsigned u3 = feat[(size_t)c3 * L + j];
        a0 += (bf2f(u0 & 0xffff) + bf2f(u1 & 0xffff)) + (bf2f(u2 & 0xffff) + bf2f(u3 & 0xffff));
        a1 += (bf2f((unsigned short)(u0 >> 16)) + bf2f((unsigned short)(u1 >> 16)))
            + (bf2f((unsigned short)(u2 >> 16)) + bf2f((unsigned short)(u3 >> 16)));
    }
    for (; e < end; ++e) {
        unsigned u = feat[(size_t)colbuf[e] * L + j];
        a0 += bf2f(u & 0xffff);
        a1 += bf2f((unsigned short)(u >> 16));
    }
    float sc = scale ? scale[node] : 1.0f;
    float r0 = a0 * sc + bias[2 * j];
    float r1 = a1 * sc + bias[2 * j + 1];
    if (RELU) { r0 = fmaxf(r0, 0.f); r1 = fmaxf(r1, 0.f); }
    *(float2*)&out[(size_t)node * ldo + col_off + 2 * j] = make_float2(r0, r1);
}

// ---------------- launch ----------------
extern "C" void kernel_launch(void* const* d_in, const int* in_sizes, int n_in,
                              void* d_out, int out_size, void* d_ws, size_t ws_size,
                              hipStream_t stream) {
    const float* feat = (const float*)d_in[0];
    const int*   src  = (const int*)d_in[1];
    const int*   dst  = (const int*)d_in[2];
    const float* W1   = (const float*)d_in[3];
    const float* b1   = (const float*)d_in[4];
    const float* W2   = (const float*)d_in[5];
    const float* b2   = (const float*)d_in[6];
    const float* W3   = (const float*)d_in[7];
    const float* b3   = (const float*)d_in[8];
    const float* Wm   = (const float*)d_in[9];
    const float* bm   = (const float*)d_in[10];
    float* out = (float*)d_out;

    const int N = in_sizes[0] / IN_FEATS;   // 100000
    const int E = in_sizes[1];              // 1600000
    const int NBUCK = (N + 511) >> BSH;     // 196

    // workspace carve (256B-aligned regions)
    char* wsp = (char*)d_ws;
    auto alloc = [&](size_t bytes) {
        void* p = (void*)wsp;
        wsp += ((bytes + 255) / 256) * 256;
        return p;
    };
    int*   cnt_out  = (int*)alloc((size_t)N * 4);
    int*   cnt_in   = (int*)alloc((size_t)N * 4);
    int*   indptr   = (int*)alloc((size_t)(N + 1) * 4);
    int*   colbuf   = (int*)alloc((size_t)E * 4);
    int*   bhd      = (int*)alloc((size_t)NBLK * NB * 4);
    int*   bhs      = (int*)alloc((size_t)NBLK * NB * 4);
    int*   totd     = (int*)alloc(256 * 4);
    int*   tots     = (int*)alloc(256 * 4);
    int*   based    = (int*)alloc(257 * 4);
    int*   bases    = (int*)alloc(257 * 4);
    float* do_isqrt = (float*)alloc((size_t)N * 4);
    float* di_isqrt = (float*)alloc((size_t)N * 4);
    float* H        = (float*)alloc((size_t)N * JK * 4);
    int2*  pairbuf  = (int2*)alloc((size_t)E * 8);    // aliased by tmp after CSR build
    int*   srctmp   = (int*)alloc((size_t)E * 4);     // aliased by P after cnt build
    unsigned short* tmp = (unsigned short*)pairbuf;   // N*HID bf16 = 12.8MB <= E*8
    unsigned short* P   = (unsigned short*)srctmp;    // N*OUTF bf16 = 6.4MB <= E*4

    // ---- CSR + degree build (no global atomics) ----
    p1_hist<<<NBLK, 256, 0, stream>>>(src, dst, E, bhd, bhs);
    p2a_tot<<<512, 256, 0, stream>>>(bhd, bhs, totd, tots, NBLK);
    p2b_scan<<<2, 256, 0, stream>>>(totd, tots, based, bases);
    p2c_off<<<512, 256, 0, stream>>>(bhd, bhs, based, bases, NBLK);
    p3_scatter<<<NBLK, 256, 0, stream>>>(src, dst, E, bhd, bhs, pairbuf, srctmp);
    p4_csr<<<NBUCK, 256, 0, stream>>>(pairbuf, based, indptr, cnt_in, colbuf, N, E);
    p4s_cnt<<<NBUCK, 256, 0, stream>>>(srctmp, bases, cnt_out, N);
    scale_kernel<<<(N + 255) / 256, 256, 0, stream>>>(cnt_out, cnt_in, do_isqrt, di_isqrt, N);

    // ---- layers ----
    gemm_kernel<HID, IN_FEATS><<<(N + 63) / 64, 256, 0, stream>>>(feat, IN_FEATS, W1, do_isqrt, tmp, HID, N);
    gather_kernel<HID, true><<<(N + 7) / 8, 256, 0, stream>>>(indptr, colbuf, (const unsigned int*)tmp, di_isqrt, b1, H, JK, 0, N);
    gemm_kernel<HID, HID><<<(N + 63) / 64, 256, 0, stream>>>(H, JK, W2, do_isqrt, tmp, HID, N);
    gather_kernel<HID, true><<<(N + 7) / 8, 256, 0, stream>>>(indptr, colbuf, (const unsigned int*)tmp, di_isqrt, b2, H, JK, HID, N);
    gemm_kernel<HID, HID><<<(N + 63) / 64, 256, 0, stream>>>(H + HID, JK, W3, do_isqrt, tmp, HID, N);
    gather_kernel<HID, true><<<(N + 7) / 8, 256, 0, stream>>>(indptr, colbuf, (const unsigned int*)tmp, di_isqrt, b3, H, JK, 2 * HID, N);
    // JK projection BEFORE final aggregation (linearity): P = H @ Wm
    gemm_kernel<OUTF, JK><<<(N + 127) / 128, 256, 0, stream>>>(H, JK, Wm, nullptr, P, OUTF, N);
    // final un-normalized aggregation + bias
    gather_kernel<OUTF, false><<<(N + 15) / 16, 256, 0, stream>>>(indptr, colbuf, (const unsigned int*)P, nullptr, bm, out, OUTF, 0, N);
}

// Round 5
// 295.993 us; speedup vs baseline: 2.1654x; 1.2745x over previous
//
#include <hip/hip_runtime.h>

#define IN_FEATS 256
#define HID 64
#define OUTF 32
#define JK (3*HID)

#define NB   256   // buckets (allocated); actual used = (N+511)>>9
#define BSH  9     // bucket covers 512 nodes
#define NBLK 512   // edge-chunk blocks for hist/scatter

typedef __attribute__((ext_vector_type(4))) float floatx4;
typedef __attribute__((ext_vector_type(8))) short shortx8;

// ---------------- bf16 helpers (RNE) ----------------
__device__ inline unsigned short f2bf(float f) {
    unsigned u = __float_as_uint(f);
    unsigned r = (u + 0x7fffu + ((u >> 16) & 1u)) >> 16;
    return (unsigned short)r;
}
__device__ inline float bf2f(unsigned short u) {
    return __uint_as_float(((unsigned)u) << 16);
}

// ---------------- P1: per-block LDS histograms over dst-buckets and src-buckets ----
__global__ __launch_bounds__(256) void p1_hist(const int* __restrict__ src,
                                               const int* __restrict__ dst, int E,
                                               int* __restrict__ bhd, int* __restrict__ bhs) {
    __shared__ int hd[NB], hs[NB];
    int b = blockIdx.x;
    for (int t = threadIdx.x; t < NB; t += 256) { hd[t] = 0; hs[t] = 0; }
    __syncthreads();
    int cb = (E + NBLK - 1) / NBLK;
    int beg = b * cb, end = min(beg + cb, E);
    for (int e = beg + threadIdx.x; e < end; e += 256) {
        atomicAdd(&hd[dst[e] >> BSH], 1);
        atomicAdd(&hs[src[e] >> BSH], 1);
    }
    __syncthreads();
    for (int t = threadIdx.x; t < NB; t += 256) {
        bhd[b * NB + t] = hd[t];
        bhs[b * NB + t] = hs[t];
    }
}

// ---------------- P2a: per-(side,bucket) totals over block-histograms ----------------
__global__ __launch_bounds__(256) void p2a_tot(const int* __restrict__ bhd,
                                               const int* __restrict__ bhs,
                                               int* __restrict__ totd, int* __restrict__ tots,
                                               int nblk) {
    __shared__ int s[256];
    int side = blockIdx.x >> 8;     // grid = 512
    int t = blockIdx.x & 255;
    const int* bh = side ? bhs : bhd;
    int acc = 0;
    for (int k = threadIdx.x; k < nblk; k += 256) acc += bh[k * NB + t];
    s[threadIdx.x] = acc;
    __syncthreads();
    for (int off = 128; off > 0; off >>= 1) {
        if (threadIdx.x < off) s[threadIdx.x] += s[threadIdx.x + off];
        __syncthreads();
    }
    if (threadIdx.x == 0) (side ? tots : totd)[t] = s[0];
}

// ---------------- P2b: exclusive scan over bucket totals -> based/bases ----------------
__global__ __launch_bounds__(256) void p2b_scan(const int* __restrict__ totd,
                                                const int* __restrict__ tots,
                                                int* __restrict__ based, int* __restrict__ bases) {
    __shared__ int s[256];
    const int* tot = blockIdx.x ? tots : totd;
    int* bb = blockIdx.x ? bases : based;
    int t = threadIdx.x;
    int v = tot[t];
    s[t] = v;
    __syncthreads();
    for (int off = 1; off < 256; off <<= 1) {
        int u = (t >= off) ? s[t - off] : 0;
        __syncthreads();
        s[t] += u;
        __syncthreads();
    }
    bb[t] = s[t] - v;
    if (t == 255) bb[256] = s[255];
}

// ---------------- P2c: per-bucket prefix over blocks (in place) ----------------
__global__ __launch_bounds__(256) void p2c_off(int* __restrict__ bhd, int* __restrict__ bhs,
                                               const int* __restrict__ based,
                                               const int* __restrict__ bases, int nblk) {
    __shared__ int s[256];
    int side = blockIdx.x >> 8;     // grid = 512
    int t = blockIdx.x & 255;
    int* bh = side ? bhs : bhd;
    int carry = (side ? bases : based)[t];
    for (int k0 = 0; k0 < nblk; k0 += 256) {
        int k = k0 + threadIdx.x;
        int v = (k < nblk) ? bh[k * NB + t] : 0;
        s[threadIdx.x] = v;
        __syncthreads();
        for (int off = 1; off < 256; off <<= 1) {
            int u = (threadIdx.x >= off) ? s[threadIdx.x - off] : 0;
            __syncthreads();
            s[threadIdx.x] += u;
            __syncthreads();
        }
        if (k < nblk) bh[k * NB + t] = carry + s[threadIdx.x] - v;
        int tot = s[255];
        __syncthreads();
        carry += tot;
    }
}

// ---------------- P3: partition edges by bucket (LDS cursors, no global atomics) ----
__global__ __launch_bounds__(256) void p3_scatter(const int* __restrict__ src,
                                                  const int* __restrict__ dst, int E,
                                                  const int* __restrict__ bhd,
                                                  const int* __restrict__ bhs,
                                                  int2* __restrict__ pairbuf,
                                                  int* __restrict__ srctmp) {
    __shared__ int curd[NB], curs[NB];
    int b = blockIdx.x;
    for (int t = threadIdx.x; t < NB; t += 256) {
        curd[t] = bhd[b * NB + t];
        curs[t] = bhs[b * NB + t];
    }
    __syncthreads();
    int cb = (E + NBLK - 1) / NBLK;
    int beg = b * cb, end = min(beg + cb, E);
    for (int e = beg + threadIdx.x; e < end; e += 256) {
        int d = dst[e], sv = src[e];
        int pd = atomicAdd(&curd[d >> BSH], 1);
        pairbuf[pd] = make_int2(d, sv);
        int ps = atomicAdd(&curs[sv >> BSH], 1);
        srctmp[ps] = sv;
    }
}

// ---------------- P4: per-bucket CSR build (count -> scan -> place) ----------------
__global__ __launch_bounds__(256) void p4_csr(const int2* __restrict__ pairbuf,
                                              const int* __restrict__ based,
                                              int* __restrict__ indptr, int* __restrict__ cnt_in,
                                              int* __restrict__ colbuf, int N, int E) {
    __shared__ int cnt[512], lp[512], s[256];
    int b = blockIdx.x;
    int nbase = b << BSH;
    int nn = min(512, N - nbase);
    int t = threadIdx.x;
    cnt[t] = 0; cnt[t + 256] = 0;
    __syncthreads();
    int eb = based[b], ee = based[b + 1];
    for (int e = eb + t; e < ee; e += 256)
        atomicAdd(&cnt[pairbuf[e].x - nbase], 1);
    __syncthreads();
    // exclusive scan over 512 counts (thread t owns 2t, 2t+1)
    int a0 = cnt[2 * t], a1 = cnt[2 * t + 1];
    int psum = a0 + a1;
    s[t] = psum;
    __syncthreads();
    for (int off = 1; off < 256; off <<= 1) {
        int v = (t >= off) ? s[t - off] : 0;
        __syncthreads();
        s[t] += v;
        __syncthreads();
    }
    int ebase = s[t] - psum;
    lp[2 * t] = ebase;
    lp[2 * t + 1] = ebase + a0;
    __syncthreads();
    for (int i = t; i < nn; i += 256) {
        indptr[nbase + i] = eb + lp[i];
        cnt_in[nbase + i] = cnt[i];
    }
    if (b == 0 && t == 0) indptr[N] = E;
    __syncthreads();
    // place edges using lp as cursors
    for (int e = eb + t; e < ee; e += 256) {
        int2 p = pairbuf[e];
        int pos = atomicAdd(&lp[p.x - nbase], 1);
        colbuf[eb + pos] = p.y;
    }
}

// ---------------- P4s: per-bucket out-degree counts ----------------
__global__ __launch_bounds__(256) void p4s_cnt(const int* __restrict__ srctmp,
                                               const int* __restrict__ bases,
                                               int* __restrict__ cnt_out, int N) {
    __shared__ int cnt[512];
    int b = blockIdx.x;
    int nbase = b << BSH;
    int nn = min(512, N - nbase);
    int t = threadIdx.x;
    cnt[t] = 0; cnt[t + 256] = 0;
    __syncthreads();
    int eb = bases[b], ee = bases[b + 1];
    for (int e = eb + t; e < ee; e += 256)
        atomicAdd(&cnt[srctmp[e] - nbase], 1);
    __syncthreads();
    for (int i = t; i < nn; i += 256) cnt_out[nbase + i] = cnt[i];
}

__global__ void scale_kernel(const int* __restrict__ cnt_out, const int* __restrict__ cnt_in,
                             float* __restrict__ do_isqrt, float* __restrict__ di_isqrt, int N) {
    int i = blockIdx.x * blockDim.x + threadIdx.x;
    if (i < N) {
        int co = cnt_out[i]; if (co < 1) co = 1;
        int ci = cnt_in[i];  if (ci < 1) ci = 1;
        do_isqrt[i] = rsqrtf((float)co);
        di_isqrt[i] = rsqrtf((float)ci);
    }
}

// ---------------- weight prep: bf16 transposed [col][K] ----------------
__global__ __launch_bounds__(256) void wprep(const float* __restrict__ W1, const float* __restrict__ W2,
                                             const float* __restrict__ W3, const float* __restrict__ Wm,
                                             unsigned short* __restrict__ W1t, unsigned short* __restrict__ W2t,
                                             unsigned short* __restrict__ W3t, unsigned short* __restrict__ Wmt) {
    int i = blockIdx.x * 256 + threadIdx.x;
    if (i < 256 * 64) { int k = i / 64, c = i % 64; W1t[c * 256 + k] = f2bf(W1[i]); return; }
    int j = i - 256 * 64;
    if (j < 64 * 64) { int k = j / 64, c = j % 64; W2t[c * 64 + k] = f2bf(W2[j]); return; }
    int j2 = j - 64 * 64;
    if (j2 < 64 * 64) { int k = j2 / 64, c = j2 % 64; W3t[c * 64 + k] = f2bf(W3[j2]); return; }
    int j3 = j2 - 64 * 64;
    if (j3 < 192 * 32) { int k = j3 / 32, c = j3 % 32; Wmt[c * 192 + k] = f2bf(Wm[j3]); }
}

// ---------------- MFMA GEMM: out_bf16[nrows][COLS] = (X .* rs) @ Wt^T ----------------
// Wt is bf16 [COLS][K]. Block: 256 threads = 4 waves; tile 64 rows x COLS.
// Wave w computes rows w*16..w*16+15, all COLS (NFRAG n-fragments of 16).
// k-permutation invariance: A and B fragments staged with the same canonical
// k=(g*8+j) ordering -> correct result independent of HW internal k order.
template <int COLS, int K, bool SRC_F32>
__global__ __launch_bounds__(256) void mgemm(
    const void* __restrict__ Xv, int ldx,
    const unsigned short* __restrict__ Wt,
    const float* __restrict__ rs,            // may be null
    unsigned short* __restrict__ out, int ldo, int nrows) {
    constexpr int KC = 64;
    constexpr int NFRAG = COLS / 16;
    __shared__ unsigned short Al[64 * KC];    // XOR-swizzled: off ^= (row&7)<<3 (ushort units)
    __shared__ unsigned short Bl[COLS * KC];

    const int tid = threadIdx.x;
    const int wave = tid >> 6, lane = tid & 63;
    const int g = lane >> 4, lm = lane & 15;
    const int gr0 = blockIdx.x * 64;

    floatx4 acc[NFRAG];
    #pragma unroll
    for (int f = 0; f < NFRAG; ++f) acc[f] = (floatx4)0.f;

    for (int kc = 0; kc < K; kc += KC) {
        // stage A: 64 rows x 64 k, 16B chunks
        for (int c = tid; c < 64 * 8; c += 256) {
            int row = c >> 3, c8 = c & 7;
            int grow = gr0 + row;
            unsigned short v[8];
            if (grow < nrows) {
                if (SRC_F32) {
                    const float* Xf = (const float*)Xv + (size_t)grow * ldx + kc + c8 * 8;
                    float sc = rs ? rs[grow] : 1.f;
                    #pragma unroll
                    for (int j = 0; j < 8; ++j) v[j] = f2bf(Xf[j] * sc);
                } else {
                    const unsigned short* Xh = (const unsigned short*)Xv + (size_t)grow * ldx + kc + c8 * 8;
                    uint4 raw = *(const uint4*)Xh;
                    unsigned short* rp = (unsigned short*)&raw;
                    if (rs) {
                        float sc = rs[grow];
                        #pragma unroll
                        for (int j = 0; j < 8; ++j) v[j] = f2bf(bf2f(rp[j]) * sc);
                    } else {
                        #pragma unroll
                        for (int j = 0; j < 8; ++j) v[j] = rp[j];
                    }
                }
            } else {
                #pragma unroll
                for (int j = 0; j < 8; ++j) v[j] = 0;
            }
            int off = (row * KC + c8 * 8) ^ ((row & 7) << 3);
            *(uint4*)&Al[off] = *(uint4*)v;
        }
        // stage B: COLS cols x 64 k
        for (int c = tid; c < COLS * 8; c += 256) {
            int col = c >> 3, c8 = c & 7;
            uint4 raw = *(const uint4*)&Wt[(size_t)col * K + kc + c8 * 8];
            int off = (col * KC + c8 * 8) ^ ((col & 7) << 3);
            *(uint4*)&Bl[off] = raw;
        }
        __syncthreads();
        #pragma unroll
        for (int ks = 0; ks < 2; ++ks) {
            int arow = wave * 16 + lm;
            int aoff = (arow * KC + ks * 32 + g * 8) ^ ((arow & 7) << 3);
            shortx8 afrag = *(shortx8*)&Al[aoff];
            #pragma unroll
            for (int f = 0; f < NFRAG; ++f) {
                int col = f * 16 + lm;
                int boff = (col * KC + ks * 32 + g * 8) ^ ((col & 7) << 3);
                shortx8 bfrag = *(shortx8*)&Bl[boff];
                acc[f] = __builtin_amdgcn_mfma_f32_16x16x32_bf16(afrag, bfrag, acc[f], 0, 0, 0);
            }
        }
        __syncthreads();
    }
    // epilogue: D lane map (m89-verified): col = lane&15, row = (lane>>4)*4 + reg
    #pragma unroll
    for (int f = 0; f < NFRAG; ++f) {
        #pragma unroll
        for (int r = 0; r < 4; ++r) {
            int grow = gr0 + wave * 16 + g * 4 + r;
            if (grow < nrows) out[(size_t)grow * ldo + f * 16 + lm] = f2bf(acc[f][r]);
        }
    }
}

// ---------------- CSR gather aggregation (bf16x2 rows, fused scale+bias+relu) -------
// F/2 lanes per node; lane j handles columns 2j, 2j+1.
// OBF16: output packed bf16x2 to uint array (ldo/col_off in uint units);
// else: output f32 (float2), ldo/col_off in float units.
template <int F, bool RELU, bool OBF16>
__global__ __launch_bounds__(256) void gather_kernel(
    const int* __restrict__ indptr, const int* __restrict__ colbuf,
    const unsigned int* __restrict__ feat,     // bf16x2 [*, F/2]
    const float* __restrict__ scale,           // may be null
    const float* __restrict__ bias,            // [F]
    void* __restrict__ outp, int ldo, int col_off, int N) {
    constexpr int L = F / 2;
    constexpr int NPB = 256 / L;
    int j = threadIdx.x % L;
    int node = blockIdx.x * NPB + threadIdx.x / L;
    if (node >= N) return;
    int beg = indptr[node], end = indptr[node + 1];
    float a0 = 0.f, a1 = 0.f;
    int e = beg;
    for (; e + 4 <= end; e += 4) {
        int c0 = colbuf[e], c1 = colbuf[e + 1], c2 = colbuf[e + 2], c3 = colbuf[e + 3];
        unsigned u0 = feat[(size_t)c0 * L + j];
        unsigned u1 = feat[(size_t)c1 * L + j];
        unsigned u2 = feat[(size_t)c2 * L + j];
        unsigned u3 = feat[(size_t)c3 * L + j];
        a0 += (bf2f(u0 & 0xffff) + bf2f(u1 & 0xffff)) + (bf2f(u2 & 0xffff) + bf2f(u3 & 0xffff));
        a1 += (bf2f((unsigned short)(u0 >> 16)) + bf2f((unsigned short)(u1 >> 16)))
            + (bf2f((unsigned short)(u2 >> 16)) + bf2f((unsigned short)(u3 >> 16)));
    }
    for (; e < end; ++e) {
        unsigned u = feat[(size_t)colbuf[e] * L + j];
        a0 += bf2f(u & 0xffff);
        a1 += bf2f((unsigned short)(u >> 16));
    }
    float sc = scale ? scale[node] : 1.0f;
    float r0 = a0 * sc + bias[2 * j];
    float r1 = a1 * sc + bias[2 * j + 1];
    if (RELU) { r0 = fmaxf(r0, 0.f); r1 = fmaxf(r1, 0.f); }
    if (OBF16) {
        unsigned pack = (unsigned)f2bf(r0) | ((unsigned)f2bf(r1) << 16);
        ((unsigned*)outp)[(size_t)node * ldo + col_off + j] = pack;
    } else {
        *(float2*)&((float*)outp)[(size_t)node * ldo + col_off + 2 * j] = make_float2(r0, r1);
    }
}

// ---------------- launch ----------------
extern "C" void kernel_launch(void* const* d_in, const int* in_sizes, int n_in,
                              void* d_out, int out_size, void* d_ws, size_t ws_size,
                              hipStream_t stream) {
    const float* feat = (const float*)d_in[0];
    const int*   src  = (const int*)d_in[1];
    const int*   dst  = (const int*)d_in[2];
    const float* W1   = (const float*)d_in[3];
    const float* b1   = (const float*)d_in[4];
    const float* W2   = (const float*)d_in[5];
    const float* b2   = (const float*)d_in[6];
    const float* W3   = (const float*)d_in[7];
    const float* b3   = (const float*)d_in[8];
    const float* Wm   = (const float*)d_in[9];
    const float* bm   = (const float*)d_in[10];
    float* out = (float*)d_out;

    const int N = in_sizes[0] / IN_FEATS;   // 100000
    const int E = in_sizes[1];              // 1600000
    const int NBUCK = (N + 511) >> BSH;     // 196

    // workspace carve (256B-aligned regions)
    char* wsp = (char*)d_ws;
    auto alloc = [&](size_t bytes) {
        void* p = (void*)wsp;
        wsp += ((bytes + 255) / 256) * 256;
        return p;
    };
    int*   cnt_out  = (int*)alloc((size_t)N * 4);
    int*   cnt_in   = (int*)alloc((size_t)N * 4);
    int*   indptr   = (int*)alloc((size_t)(N + 1) * 4);
    int*   colbuf   = (int*)alloc((size_t)E * 4);
    int*   bhd      = (int*)alloc((size_t)NBLK * NB * 4);
    int*   bhs      = (int*)alloc((size_t)NBLK * NB * 4);
    int*   totd     = (int*)alloc(256 * 4);
    int*   tots     = (int*)alloc(256 * 4);
    int*   based    = (int*)alloc(257 * 4);
    int*   bases    = (int*)alloc(257 * 4);
    float* do_isqrt = (float*)alloc((size_t)N * 4);
    float* di_isqrt = (float*)alloc((size_t)N * 4);
    unsigned short* W1t = (unsigned short*)alloc(256 * 64 * 2);
    unsigned short* W2t = (unsigned short*)alloc(64 * 64 * 2);
    unsigned short* W3t = (unsigned short*)alloc(64 * 64 * 2);
    unsigned short* Wmt = (unsigned short*)alloc(192 * 32 * 2);
    unsigned short* Hb  = (unsigned short*)alloc((size_t)N * JK * 2);   // bf16 [N][192]
    int2*  pairbuf  = (int2*)alloc((size_t)E * 8);    // aliased by tmp after CSR build
    int*   srctmp   = (int*)alloc((size_t)E * 4);     // aliased by P after cnt build
    unsigned short* tmp = (unsigned short*)pairbuf;   // N*HID bf16 = 12.8MB <= E*8
    unsigned short* P   = (unsigned short*)srctmp;    // N*OUTF bf16 = 6.4MB <= E*4

    // ---- CSR + degree build (no global atomics) ----
    p1_hist<<<NBLK, 256, 0, stream>>>(src, dst, E, bhd, bhs);
    p2a_tot<<<512, 256, 0, stream>>>(bhd, bhs, totd, tots, NBLK);
    p2b_scan<<<2, 256, 0, stream>>>(totd, tots, based, bases);
    p2c_off<<<512, 256, 0, stream>>>(bhd, bhs, based, bases, NBLK);
    p3_scatter<<<NBLK, 256, 0, stream>>>(src, dst, E, bhd, bhs, pairbuf, srctmp);
    p4_csr<<<NBUCK, 256, 0, stream>>>(pairbuf, based, indptr, cnt_in, colbuf, N, E);
    p4s_cnt<<<NBUCK, 256, 0, stream>>>(srctmp, bases, cnt_out, N);
    scale_kernel<<<(N + 255) / 256, 256, 0, stream>>>(cnt_out, cnt_in, do_isqrt, di_isqrt, N);
    wprep<<<120, 256, 0, stream>>>(W1, W2, W3, Wm, W1t, W2t, W3t, Wmt);

    const int GB = (N + 63) / 64;   // 64-row GEMM tiles
    // ---- layers ----
    mgemm<HID, IN_FEATS, true><<<GB, 256, 0, stream>>>(feat, IN_FEATS, W1t, do_isqrt, tmp, HID, N);
    gather_kernel<HID, true, true><<<(N + 7) / 8, 256, 0, stream>>>(indptr, colbuf, (const unsigned int*)tmp, di_isqrt, b1, Hb, 96, 0, N);
    mgemm<HID, HID, false><<<GB, 256, 0, stream>>>(Hb, JK, W2t, do_isqrt, tmp, HID, N);
    gather_kernel<HID, true, true><<<(N + 7) / 8, 256, 0, stream>>>(indptr, colbuf, (const unsigned int*)tmp, di_isqrt, b2, Hb, 96, 32, N);
    mgemm<HID, HID, false><<<GB, 256, 0, stream>>>(Hb + HID, JK, W3t, do_isqrt, tmp, HID, N);
    gather_kernel<HID, true, true><<<(N + 7) / 8, 256, 0, stream>>>(indptr, colbuf, (const unsigned int*)tmp, di_isqrt, b3, Hb, 96, 64, N);
    // JK projection BEFORE final aggregation (linearity): P = H @ Wm
    mgemm<OUTF, JK, false><<<GB, 256, 0, stream>>>(Hb, JK, Wmt, nullptr, P, OUTF, N);
    // final un-normalized aggregation + bias (f32 output)
    gather_kernel<OUTF, false, false><<<(N + 15) / 16, 256, 0, stream>>>(indptr, colbuf, (const unsigned int*)P, nullptr, bm, out, OUTF, 0, N);
}